// Round 19
// baseline (158.141 us; speedup 1.0000x reference)
//
#include <hip/hip_runtime.h>
#include <hip/hip_bf16.h>
#include <math.h>

// LatentODE round 19: EXACT round-16 kernel (transposed K=16 MFMA chain,
// dual 16-row tiles/wave, 8192-entry bf16-pre-rounded magic-addressed tanh
// LUT, trunc pack, hoists, f32 bias-inits, bounds(256,2) -> 108 VGPR clean).
// ONE change: grid 1024 -> 2048. 4 blocks/CU are VGPR-resident; 8 assigned
// gives immediate backfill when a block retires (grid 1024 had zero refill,
// draining residency through the tail).
// Allocator map: (256,2)->108 CLEAN; (256,3)->84+spill; (256,4)->64 spill;
// (256,5)->48 remat; one-arg/none->128ok-but-slower / 64 REMAT.
// No v_cvt_pk inline asm (miscompiles).

typedef __attribute__((ext_vector_type(4))) short short4v;
typedef __attribute__((ext_vector_type(4))) float f32x4;
typedef unsigned int uint_t;
typedef unsigned short ushort_t;

__device__ __forceinline__ uint_t fu(float f) { union { float f; uint_t u; } x; x.f = f; return x.u; }
__device__ __forceinline__ float uf(uint_t u) { union { uint_t u; float f; } x; x.u = u; return x.f; }

__device__ __forceinline__ ushort_t bf16_rne(float f) {
    uint_t u = fu(f);
    u += 0x7FFFu + ((u >> 16) & 1u);
    return (ushort_t)(u >> 16);
}

// TRUNCATION pack: 2 x v_perm only. Exact for bf16-pre-rounded inputs.
__device__ __forceinline__ short4v pack4(f32x4 v) {
    uint_t lo = __builtin_amdgcn_perm(fu(v[1]), fu(v[0]), 0x07060302u);
    uint_t hi = __builtin_amdgcn_perm(fu(v[3]), fu(v[2]), 0x07060302u);
    union { uint_t u[2]; short4v s; } p;
    p.u[0] = lo; p.u[1] = hi;
    return p.s;
}

// rounding pack (x staging only, outside hot loop)
__device__ __forceinline__ short4v pack4r(f32x4 v) {
    uint_t lo = __builtin_amdgcn_perm(fu(v[1]) + 0x8000u, fu(v[0]) + 0x8000u, 0x07060302u);
    uint_t hi = __builtin_amdgcn_perm(fu(v[3]) + 0x8000u, fu(v[2]) + 0x8000u, 0x07060302u);
    union { uint_t u[2]; short4v s; } p;
    p.u[0] = lo; p.u[1] = hi;
    return p.s;
}

#define TANH_N 8192
#define TANH_B 16.0f
#define TANH_H (2.0f * TANH_B / TANH_N)         // 1/256

// magic-number nearest tanh: y = fma(x,1024,MAGIC); mantissa holds
// byte-offset; AND aligns+extracts. 2 VALU + 1 ds_read_b32.
#define TANH_MAGIC 8404994.0f
__device__ __forceinline__ float tanh_lut(const float* tab, float x) {
    float y = __builtin_fmaf(x, 1024.0f, TANH_MAGIC);
    uint_t off = fu(y) & 0x007FFFFCu;
    return *reinterpret_cast<const float*>(
        reinterpret_cast<const char*>(tab) + off);
}

__device__ __forceinline__ f32x4 mfma_k16(short4v a, short4v b, f32x4 c) {
#if __has_builtin(__builtin_amdgcn_mfma_f32_16x16x16bf16_1k)
    return __builtin_amdgcn_mfma_f32_16x16x16bf16_1k(a, b, c, 0, 0, 0);
#elif __has_builtin(__builtin_amdgcn_mfma_f32_16x16x16_bf16)
    return __builtin_amdgcn_mfma_f32_16x16x16_bf16(a, b, c, 0, 0, 0);
#else
    f32x4 d;
    asm volatile("v_mfma_f32_16x16x16_bf16 %0, %1, %2, %3"
                 : "=v"(d) : "v"(a), "v"(b), "v"(c));
    return d;
#endif
}

// A-fragment of W^T tile: lane (g,c): row m = 16t+c, k = koff+4g+j
template <typename F>
__device__ __forceinline__ short4v load_afrag(F getv, int c, int g, int koff, int t) {
    short4v r;
    #pragma unroll
    for (int j = 0; j < 4; ++j)
        r[j] = (short)bf16_rne(getv(koff + 4 * g + j, 16 * t + c));
    return r;
}

__global__ __launch_bounds__(256, 2) void latent_ode_t(
    const float* __restrict__ dt, const float* __restrict__ x,
    const float* __restrict__ jw1, const float* __restrict__ jb1,
    const float* __restrict__ jw2, const float* __restrict__ jb2,
    const float* __restrict__ ow1, const float* __restrict__ ob1,
    const float* __restrict__ ow2, const float* __restrict__ ob2,
    const float* __restrict__ mw1, const float* __restrict__ mb1,
    const float* __restrict__ mw2, const float* __restrict__ mb2,
    const float* __restrict__ sw1, const float* __restrict__ sb1,
    const float* __restrict__ sw2, const float* __restrict__ sb2,
    float* __restrict__ out, int rows)
{
    __shared__ float tab[TANH_N];

    const int tid = threadIdx.x;
    const int lane = tid & 63;
    const int g = lane >> 4, c = lane & 15;

    // ---- build tanh table, bf16-pre-rounded (once per block) ----
    for (int e = tid; e < TANH_N; e += 256) {
        float v = tanhf((e - TANH_N / 2) * TANH_H);
        tab[e] = uf((uint_t)bf16_rne(v) << 16);
    }
    __syncthreads();

    // ---- weight element getters (bias folded at the padded K-row) ----
    auto jw1e = [&](int k, int n) -> float {
        if (n >= 50) return 0.f;
        if (k < 8) return jw1[k * 50 + n];
        if (k == 8) return jb1[n];
        return 0.f;
    };
    auto jw2e = [&](int k, int n) -> float {
        if (k < 50) return jw2[k * 32 + n];
        return 0.f;   // bias via cjb2 accumulator init
    };
    auto ow1e = [&](int k, int n) -> float {
        if (n >= 50) return 0.f;
        if (k < 40) return ow1[k * 50 + n];
        if (k == 40) return ob1[n];
        return 0.f;
    };
    auto ow2e = [&](int k, int n) -> float {
        if (k < 50) return ow2[k * 32 + n];
        return 0.f;   // bias via cob2 accumulator init
    };
    auto hw1e = [&](int k, int n) -> float {
        const float* w = (n < 32) ? mw1 : sw1;
        const float* b = (n < 32) ? mb1 : sb1;
        int nn = n & 31;
        if (k < 32) return w[k * 32 + nn];
        if (k == 32) return b[nn];
        return 0.f;
    };
    auto hw2e = [&](int k, int n) -> float {
        if (n == 0) return (k < 32) ? mw2[k] : 0.f;
        if (n == 1) return (k >= 32 && k < 64) ? sw2[k - 32] : 0.f;
        return 0.f;
    };

    // ---- preload all weight A-fragments into registers ----
    short4v jw1f[4], jw2f[2][4], ow1f[4][3], ow2f[2][4], hw1f[4][3], hw2f[4];
    #pragma unroll
    for (int t = 0; t < 4; ++t) {
        jw1f[t] = load_afrag(jw1e, c, g, 0, t);
        #pragma unroll
        for (int ks = 0; ks < 3; ++ks) {
            ow1f[t][ks] = load_afrag(ow1e, c, g, 16 * ks, t);
            hw1f[t][ks] = load_afrag(hw1e, c, g, 16 * ks, t);
        }
    }
    #pragma unroll
    for (int t = 0; t < 2; ++t)
        #pragma unroll
        for (int ks = 0; ks < 4; ++ks) {
            jw2f[t][ks] = load_afrag(jw2e, c, g, 16 * ks, t);
            ow2f[t][ks] = load_afrag(ow2e, c, g, 16 * ks, t);
        }
    #pragma unroll
    for (int ks = 0; ks < 4; ++ks)
        hw2f[ks] = load_afrag(hw2e, c, g, 16 * ks, 0);

    const float mb2v = mb2[0], sb2v = sb2[0];
    const short ONE = (short)0x3F80;  // bf16(1.0)

    // constant-1 fragment for head-L1 bias K-slice (feature 32 -> g=0,j=0)
    short4v onef = {0, 0, 0, 0};
    if (g == 0) onef[0] = ONE;

    // heads-L1 bias contribution: per-lane constant, hoisted out of unit loop
    f32x4 chb[4];
    #pragma unroll
    for (int t = 0; t < 4; ++t) {
        f32x4 zro = {0.f, 0.f, 0.f, 0.f};
        chb[t] = mfma_k16(hw1f[t][2], onef, zro);
    }

    // L2 biases as f32 accumulator inits (feature = 16t + 4g + r)
    f32x4 cob2[2], cjb2[2];
    #pragma unroll
    for (int t = 0; t < 2; ++t)
        #pragma unroll
        for (int r = 0; r < 4; ++r) {
            int n = 16 * t + 4 * g + r;
            cob2[t][r] = ob2[n];
            cjb2[t][r] = jb2[n];
        }

    const int nunits = rows >> 5;  // 32 rows per unit (2 tiles)
    const int nwaves = (gridDim.x * blockDim.x) >> 6;
    const int wuid = (blockIdx.x * blockDim.x + tid) >> 6;

    for (int unit = wuid; unit < nunits; unit += nwaves) {
        const int row0 = unit << 5;

        // per-tile x B-fragments and scales
        short4v xb[2];
        float sv[2];
        #pragma unroll
        for (int p = 0; p < 2; ++p) {
            const int rp = row0 + 16 * p;
            short4v xv4 = {0, 0, 0, 0};
            if (g < 2) {
                const float4 xv = *reinterpret_cast<const float4*>(
                    &x[(size_t)(rp + c) * 8 + 4 * g]);
                f32x4 q = {xv.x, xv.y, xv.z, xv.w};
                xv4 = pack4r(q);
            } else if (g == 2) {
                xv4[0] = ONE;
            }
            xb[p] = xv4;
            const float2 dv = *reinterpret_cast<const float2*>(&dt[2 * (size_t)(rp + c)]);
            sv[p] = (dv.y - dv.x) * (1.0f / 240.0f);
        }

        // ---- jumpNN L1: h = tanh(jw1^T x + jb1) ----
        short4v hf[2][4];
        #pragma unroll
        for (int t = 0; t < 4; ++t) {
            #pragma unroll
            for (int p = 0; p < 2; ++p) {
                f32x4 a = {0.f, 0.f, 0.f, 0.f};
                a = mfma_k16(jw1f[t], xb[p], a);
                f32x4 v;
                #pragma unroll
                for (int r = 0; r < 4; ++r) v[r] = tanh_lut(tab, a[r]);
                hf[p][t] = pack4(v);
            }
        }

        // ---- jumpNN L2: z0 = tanh(jw2^T h + jb2) ----
        f32x4 zm[2][2];
        short4v zf[2][2];
        #pragma unroll
        for (int t = 0; t < 2; ++t) {
            #pragma unroll
            for (int p = 0; p < 2; ++p) {
                f32x4 a = mfma_k16(jw2f[t][0], hf[p][0], cjb2[t]);
                #pragma unroll
                for (int ks = 1; ks < 4; ++ks) a = mfma_k16(jw2f[t][ks], hf[p][ks], a);
                #pragma unroll
                for (int r = 0; r < 4; ++r) zm[p][t][r] = tanh_lut(tab, a[r]);
                zf[p][t] = pack4(zm[p][t]);
            }
        }

        // ---- Euler L1 x-contribution (step-invariant): hoisted ----
        f32x4 cxb[4][2];
        #pragma unroll
        for (int t = 0; t < 4; ++t)
            #pragma unroll
            for (int p = 0; p < 2; ++p) {
                f32x4 zro = {0.f, 0.f, 0.f, 0.f};
                cxb[t][p] = mfma_k16(ow1f[t][2], xb[p], zro);
            }

        // ---- 10 Euler steps (dual-tile interleaved) ----
        #pragma unroll 1
        for (int step = 0; step < 10; ++step) {
            #pragma unroll
            for (int t = 0; t < 4; ++t) {
                #pragma unroll
                for (int p = 0; p < 2; ++p) {
                    f32x4 a = mfma_k16(ow1f[t][0], zf[p][0], cxb[t][p]);
                    a = mfma_k16(ow1f[t][1], zf[p][1], a);
                    f32x4 v;
                    #pragma unroll
                    for (int r = 0; r < 4; ++r) v[r] = fmaxf(a[r], 0.0f);
                    hf[p][t] = pack4(v);
                }
            }
            #pragma unroll
            for (int t = 0; t < 2; ++t) {
                #pragma unroll
                for (int p = 0; p < 2; ++p) {
                    f32x4 a = mfma_k16(ow2f[t][0], hf[p][0], cob2[t]);
                    #pragma unroll
                    for (int ks = 1; ks < 4; ++ks) a = mfma_k16(ow2f[t][ks], hf[p][ks], a);
                    #pragma unroll
                    for (int r = 0; r < 4; ++r)
                        zm[p][t][r] = __builtin_fmaf(sv[p], tanh_lut(tab, a[r]), zm[p][t][r]);
                    zf[p][t] = pack4(zm[p][t]);
                }
            }
        }

        // ---- heads L1: [tanh(mw1^T z + mb1); tanh(sw1^T z + sb1)] ----
        short4v hh[2][4];
        #pragma unroll
        for (int t = 0; t < 4; ++t) {
            #pragma unroll
            for (int p = 0; p < 2; ++p) {
                f32x4 a = mfma_k16(hw1f[t][0], zf[p][0], chb[t]);
                a = mfma_k16(hw1f[t][1], zf[p][1], a);
                f32x4 v;
                #pragma unroll
                for (int r = 0; r < 4; ++r) v[r] = tanh_lut(tab, a[r]);
                hh[p][t] = pack4(v);
            }
        }
        // ---- heads L2: row0 = mu, row1 = sigma ----
        #pragma unroll
        for (int p = 0; p < 2; ++p) {
            f32x4 o = {0.f, 0.f, 0.f, 0.f};
            #pragma unroll
            for (int ks = 0; ks < 4; ++ks) o = mfma_k16(hw2f[ks], hh[p][ks], o);
            if (lane < 16) {
                const int rp = row0 + 16 * p;
                out[rp + c] = o[0] + mb2v;
                float v2 = o[1] + sb2v;
                out[rows + rp + c] = fmaxf(v2, 0.0f) +
                    0.69314718055994531f *
                    __builtin_log2f(1.0f + __builtin_exp2f(-fabsf(v2) * 1.4426950408889634f));
            }
        }
    }
}

extern "C" void kernel_launch(void* const* d_in, const int* in_sizes, int n_in,
                              void* d_out, int out_size, void* d_ws, size_t ws_size,
                              hipStream_t stream) {
    const float* dt  = (const float*)d_in[0];
    const float* x   = (const float*)d_in[1];
    const float* jw1 = (const float*)d_in[2];
    const float* jb1 = (const float*)d_in[3];
    const float* jw2 = (const float*)d_in[4];
    const float* jb2 = (const float*)d_in[5];
    const float* ow1 = (const float*)d_in[6];
    const float* ob1 = (const float*)d_in[7];
    const float* ow2 = (const float*)d_in[8];
    const float* ob2 = (const float*)d_in[9];
    const float* mw1 = (const float*)d_in[10];
    const float* mb1 = (const float*)d_in[11];
    const float* mw2 = (const float*)d_in[12];
    const float* mb2 = (const float*)d_in[13];
    const float* sw1 = (const float*)d_in[14];
    const float* sb1 = (const float*)d_in[15];
    const float* sw2 = (const float*)d_in[16];
    const float* sb2 = (const float*)d_in[17];
    float* out = (float*)d_out;

    const int rows = in_sizes[1] / 8;  // B*T = 819200
    const int grid = 2048;             // 8 blocks/CU assigned, 4 resident + backfill
    hipLaunchKernelGGL(latent_ode_t, dim3(grid), dim3(256), 0, stream,
                       dt, x, jw1, jb1, jw2, jb2, ow1, ob1, ow2, ob2,
                       mw1, mb1, mw2, mb2, sw1, sb1, sw2, sb2, out, rows);
}

// Round 20
// 132.228 us; speedup vs baseline: 1.1960x; 1.1960x over previous
//
#include <hip/hip_runtime.h>
#include <hip/hip_bf16.h>
#include <math.h>

// LatentODE round 20: EXACT round-16 kernel (best: 146us; transposed K=16
// MFMA chain, dual 16-row tiles/wave, 8192-entry bf16-pre-rounded magic-
// addressed tanh LUT, trunc pack, hoists, f32 bias-inits, bounds(256,2),
// grid 1024) with ONE change: Euler-L1 relu done on PACKED bf16 via
// int16-max (bf16 sign bit == int16 sign; max_i16(x,0) zeroes negatives
// incl -0): 4 v_max_f32 + 2 perm -> 2 perm + 2 pk_max_i16 per group.
// Occupancy axis exhausted (R17/18/19); VGPR-ILP axis exhausted (quad-tile
// needs ~300 VGPR). No v_cvt_pk inline asm (miscompiles).

typedef __attribute__((ext_vector_type(4))) short short4v;
typedef __attribute__((ext_vector_type(2))) short s16x2;
typedef __attribute__((ext_vector_type(4))) float f32x4;
typedef unsigned int uint_t;
typedef unsigned short ushort_t;

__device__ __forceinline__ uint_t fu(float f) { union { float f; uint_t u; } x; x.f = f; return x.u; }
__device__ __forceinline__ float uf(uint_t u) { union { uint_t u; float f; } x; x.u = u; return x.f; }

__device__ __forceinline__ ushort_t bf16_rne(float f) {
    uint_t u = fu(f);
    u += 0x7FFFu + ((u >> 16) & 1u);
    return (ushort_t)(u >> 16);
}

// TRUNCATION pack: 2 x v_perm only. Exact for bf16-pre-rounded inputs.
__device__ __forceinline__ short4v pack4(f32x4 v) {
    uint_t lo = __builtin_amdgcn_perm(fu(v[1]), fu(v[0]), 0x07060302u);
    uint_t hi = __builtin_amdgcn_perm(fu(v[3]), fu(v[2]), 0x07060302u);
    union { uint_t u[2]; short4v s; } p;
    p.u[0] = lo; p.u[1] = hi;
    return p.s;
}

// trunc-pack + packed bf16 relu (int16 max vs 0 per 16-bit half)
__device__ __forceinline__ short4v relu_pack4(f32x4 v) {
    uint_t lo = __builtin_amdgcn_perm(fu(v[1]), fu(v[0]), 0x07060302u);
    uint_t hi = __builtin_amdgcn_perm(fu(v[3]), fu(v[2]), 0x07060302u);
    s16x2 zl = {0, 0};
    s16x2 a = __builtin_elementwise_max(__builtin_bit_cast(s16x2, lo), zl);
    s16x2 b = __builtin_elementwise_max(__builtin_bit_cast(s16x2, hi), zl);
    union { uint_t u[2]; short4v s; } p;
    p.u[0] = __builtin_bit_cast(uint_t, a);
    p.u[1] = __builtin_bit_cast(uint_t, b);
    return p.s;
}

// rounding pack (x staging only, outside hot loop)
__device__ __forceinline__ short4v pack4r(f32x4 v) {
    uint_t lo = __builtin_amdgcn_perm(fu(v[1]) + 0x8000u, fu(v[0]) + 0x8000u, 0x07060302u);
    uint_t hi = __builtin_amdgcn_perm(fu(v[3]) + 0x8000u, fu(v[2]) + 0x8000u, 0x07060302u);
    union { uint_t u[2]; short4v s; } p;
    p.u[0] = lo; p.u[1] = hi;
    return p.s;
}

#define TANH_N 8192
#define TANH_B 16.0f
#define TANH_H (2.0f * TANH_B / TANH_N)         // 1/256

// magic-number nearest tanh: y = fma(x,1024,MAGIC); mantissa holds
// byte-offset; AND aligns+extracts. 2 VALU + 1 ds_read_b32.
#define TANH_MAGIC 8404994.0f
__device__ __forceinline__ float tanh_lut(const float* tab, float x) {
    float y = __builtin_fmaf(x, 1024.0f, TANH_MAGIC);
    uint_t off = fu(y) & 0x007FFFFCu;
    return *reinterpret_cast<const float*>(
        reinterpret_cast<const char*>(tab) + off);
}

__device__ __forceinline__ f32x4 mfma_k16(short4v a, short4v b, f32x4 c) {
#if __has_builtin(__builtin_amdgcn_mfma_f32_16x16x16bf16_1k)
    return __builtin_amdgcn_mfma_f32_16x16x16bf16_1k(a, b, c, 0, 0, 0);
#elif __has_builtin(__builtin_amdgcn_mfma_f32_16x16x16_bf16)
    return __builtin_amdgcn_mfma_f32_16x16x16_bf16(a, b, c, 0, 0, 0);
#else
    f32x4 d;
    asm volatile("v_mfma_f32_16x16x16_bf16 %0, %1, %2, %3"
                 : "=v"(d) : "v"(a), "v"(b), "v"(c));
    return d;
#endif
}

// A-fragment of W^T tile: lane (g,c): row m = 16t+c, k = koff+4g+j
template <typename F>
__device__ __forceinline__ short4v load_afrag(F getv, int c, int g, int koff, int t) {
    short4v r;
    #pragma unroll
    for (int j = 0; j < 4; ++j)
        r[j] = (short)bf16_rne(getv(koff + 4 * g + j, 16 * t + c));
    return r;
}

__global__ __launch_bounds__(256, 2) void latent_ode_t(
    const float* __restrict__ dt, const float* __restrict__ x,
    const float* __restrict__ jw1, const float* __restrict__ jb1,
    const float* __restrict__ jw2, const float* __restrict__ jb2,
    const float* __restrict__ ow1, const float* __restrict__ ob1,
    const float* __restrict__ ow2, const float* __restrict__ ob2,
    const float* __restrict__ mw1, const float* __restrict__ mb1,
    const float* __restrict__ mw2, const float* __restrict__ mb2,
    const float* __restrict__ sw1, const float* __restrict__ sb1,
    const float* __restrict__ sw2, const float* __restrict__ sb2,
    float* __restrict__ out, int rows)
{
    __shared__ float tab[TANH_N];

    const int tid = threadIdx.x;
    const int lane = tid & 63;
    const int g = lane >> 4, c = lane & 15;

    // ---- build tanh table, bf16-pre-rounded (once per block) ----
    for (int e = tid; e < TANH_N; e += 256) {
        float v = tanhf((e - TANH_N / 2) * TANH_H);
        tab[e] = uf((uint_t)bf16_rne(v) << 16);
    }
    __syncthreads();

    // ---- weight element getters (bias folded at the padded K-row) ----
    auto jw1e = [&](int k, int n) -> float {
        if (n >= 50) return 0.f;
        if (k < 8) return jw1[k * 50 + n];
        if (k == 8) return jb1[n];
        return 0.f;
    };
    auto jw2e = [&](int k, int n) -> float {
        if (k < 50) return jw2[k * 32 + n];
        return 0.f;   // bias via cjb2 accumulator init
    };
    auto ow1e = [&](int k, int n) -> float {
        if (n >= 50) return 0.f;
        if (k < 40) return ow1[k * 50 + n];
        if (k == 40) return ob1[n];
        return 0.f;
    };
    auto ow2e = [&](int k, int n) -> float {
        if (k < 50) return ow2[k * 32 + n];
        return 0.f;   // bias via cob2 accumulator init
    };
    auto hw1e = [&](int k, int n) -> float {
        const float* w = (n < 32) ? mw1 : sw1;
        const float* b = (n < 32) ? mb1 : sb1;
        int nn = n & 31;
        if (k < 32) return w[k * 32 + nn];
        if (k == 32) return b[nn];
        return 0.f;
    };
    auto hw2e = [&](int k, int n) -> float {
        if (n == 0) return (k < 32) ? mw2[k] : 0.f;
        if (n == 1) return (k >= 32 && k < 64) ? sw2[k - 32] : 0.f;
        return 0.f;
    };

    // ---- preload all weight A-fragments into registers ----
    short4v jw1f[4], jw2f[2][4], ow1f[4][3], ow2f[2][4], hw1f[4][3], hw2f[4];
    #pragma unroll
    for (int t = 0; t < 4; ++t) {
        jw1f[t] = load_afrag(jw1e, c, g, 0, t);
        #pragma unroll
        for (int ks = 0; ks < 3; ++ks) {
            ow1f[t][ks] = load_afrag(ow1e, c, g, 16 * ks, t);
            hw1f[t][ks] = load_afrag(hw1e, c, g, 16 * ks, t);
        }
    }
    #pragma unroll
    for (int t = 0; t < 2; ++t)
        #pragma unroll
        for (int ks = 0; ks < 4; ++ks) {
            jw2f[t][ks] = load_afrag(jw2e, c, g, 16 * ks, t);
            ow2f[t][ks] = load_afrag(ow2e, c, g, 16 * ks, t);
        }
    #pragma unroll
    for (int ks = 0; ks < 4; ++ks)
        hw2f[ks] = load_afrag(hw2e, c, g, 16 * ks, 0);

    const float mb2v = mb2[0], sb2v = sb2[0];
    const short ONE = (short)0x3F80;  // bf16(1.0)

    // constant-1 fragment for head-L1 bias K-slice (feature 32 -> g=0,j=0)
    short4v onef = {0, 0, 0, 0};
    if (g == 0) onef[0] = ONE;

    // heads-L1 bias contribution: per-lane constant, hoisted out of unit loop
    f32x4 chb[4];
    #pragma unroll
    for (int t = 0; t < 4; ++t) {
        f32x4 zro = {0.f, 0.f, 0.f, 0.f};
        chb[t] = mfma_k16(hw1f[t][2], onef, zro);
    }

    // L2 biases as f32 accumulator inits (feature = 16t + 4g + r)
    f32x4 cob2[2], cjb2[2];
    #pragma unroll
    for (int t = 0; t < 2; ++t)
        #pragma unroll
        for (int r = 0; r < 4; ++r) {
            int n = 16 * t + 4 * g + r;
            cob2[t][r] = ob2[n];
            cjb2[t][r] = jb2[n];
        }

    const int nunits = rows >> 5;  // 32 rows per unit (2 tiles)
    const int nwaves = (gridDim.x * blockDim.x) >> 6;
    const int wuid = (blockIdx.x * blockDim.x + tid) >> 6;

    for (int unit = wuid; unit < nunits; unit += nwaves) {
        const int row0 = unit << 5;

        // per-tile x B-fragments and scales
        short4v xb[2];
        float sv[2];
        #pragma unroll
        for (int p = 0; p < 2; ++p) {
            const int rp = row0 + 16 * p;
            short4v xv4 = {0, 0, 0, 0};
            if (g < 2) {
                const float4 xv = *reinterpret_cast<const float4*>(
                    &x[(size_t)(rp + c) * 8 + 4 * g]);
                f32x4 q = {xv.x, xv.y, xv.z, xv.w};
                xv4 = pack4r(q);
            } else if (g == 2) {
                xv4[0] = ONE;
            }
            xb[p] = xv4;
            const float2 dv = *reinterpret_cast<const float2*>(&dt[2 * (size_t)(rp + c)]);
            sv[p] = (dv.y - dv.x) * (1.0f / 240.0f);
        }

        // ---- jumpNN L1: h = tanh(jw1^T x + jb1) ----
        short4v hf[2][4];
        #pragma unroll
        for (int t = 0; t < 4; ++t) {
            #pragma unroll
            for (int p = 0; p < 2; ++p) {
                f32x4 a = {0.f, 0.f, 0.f, 0.f};
                a = mfma_k16(jw1f[t], xb[p], a);
                f32x4 v;
                #pragma unroll
                for (int r = 0; r < 4; ++r) v[r] = tanh_lut(tab, a[r]);
                hf[p][t] = pack4(v);
            }
        }

        // ---- jumpNN L2: z0 = tanh(jw2^T h + jb2) ----
        f32x4 zm[2][2];
        short4v zf[2][2];
        #pragma unroll
        for (int t = 0; t < 2; ++t) {
            #pragma unroll
            for (int p = 0; p < 2; ++p) {
                f32x4 a = mfma_k16(jw2f[t][0], hf[p][0], cjb2[t]);
                #pragma unroll
                for (int ks = 1; ks < 4; ++ks) a = mfma_k16(jw2f[t][ks], hf[p][ks], a);
                #pragma unroll
                for (int r = 0; r < 4; ++r) zm[p][t][r] = tanh_lut(tab, a[r]);
                zf[p][t] = pack4(zm[p][t]);
            }
        }

        // ---- Euler L1 x-contribution (step-invariant): hoisted ----
        f32x4 cxb[4][2];
        #pragma unroll
        for (int t = 0; t < 4; ++t)
            #pragma unroll
            for (int p = 0; p < 2; ++p) {
                f32x4 zro = {0.f, 0.f, 0.f, 0.f};
                cxb[t][p] = mfma_k16(ow1f[t][2], xb[p], zro);
            }

        // ---- 10 Euler steps (dual-tile interleaved) ----
        #pragma unroll 1
        for (int step = 0; step < 10; ++step) {
            #pragma unroll
            for (int t = 0; t < 4; ++t) {
                #pragma unroll
                for (int p = 0; p < 2; ++p) {
                    f32x4 a = mfma_k16(ow1f[t][0], zf[p][0], cxb[t][p]);
                    a = mfma_k16(ow1f[t][1], zf[p][1], a);
                    hf[p][t] = relu_pack4(a);   // relu on packed bf16
                }
            }
            #pragma unroll
            for (int t = 0; t < 2; ++t) {
                #pragma unroll
                for (int p = 0; p < 2; ++p) {
                    f32x4 a = mfma_k16(ow2f[t][0], hf[p][0], cob2[t]);
                    #pragma unroll
                    for (int ks = 1; ks < 4; ++ks) a = mfma_k16(ow2f[t][ks], hf[p][ks], a);
                    #pragma unroll
                    for (int r = 0; r < 4; ++r)
                        zm[p][t][r] = __builtin_fmaf(sv[p], tanh_lut(tab, a[r]), zm[p][t][r]);
                    zf[p][t] = pack4(zm[p][t]);
                }
            }
        }

        // ---- heads L1: [tanh(mw1^T z + mb1); tanh(sw1^T z + sb1)] ----
        short4v hh[2][4];
        #pragma unroll
        for (int t = 0; t < 4; ++t) {
            #pragma unroll
            for (int p = 0; p < 2; ++p) {
                f32x4 a = mfma_k16(hw1f[t][0], zf[p][0], chb[t]);
                a = mfma_k16(hw1f[t][1], zf[p][1], a);
                f32x4 v;
                #pragma unroll
                for (int r = 0; r < 4; ++r) v[r] = tanh_lut(tab, a[r]);
                hh[p][t] = pack4(v);
            }
        }
        // ---- heads L2: row0 = mu, row1 = sigma ----
        #pragma unroll
        for (int p = 0; p < 2; ++p) {
            f32x4 o = {0.f, 0.f, 0.f, 0.f};
            #pragma unroll
            for (int ks = 0; ks < 4; ++ks) o = mfma_k16(hw2f[ks], hh[p][ks], o);
            if (lane < 16) {
                const int rp = row0 + 16 * p;
                out[rp + c] = o[0] + mb2v;
                float v2 = o[1] + sb2v;
                out[rows + rp + c] = fmaxf(v2, 0.0f) +
                    0.69314718055994531f *
                    __builtin_log2f(1.0f + __builtin_exp2f(-fabsf(v2) * 1.4426950408889634f));
            }
        }
    }
}

extern "C" void kernel_launch(void* const* d_in, const int* in_sizes, int n_in,
                              void* d_out, int out_size, void* d_ws, size_t ws_size,
                              hipStream_t stream) {
    const float* dt  = (const float*)d_in[0];
    const float* x   = (const float*)d_in[1];
    const float* jw1 = (const float*)d_in[2];
    const float* jb1 = (const float*)d_in[3];
    const float* jw2 = (const float*)d_in[4];
    const float* jb2 = (const float*)d_in[5];
    const float* ow1 = (const float*)d_in[6];
    const float* ob1 = (const float*)d_in[7];
    const float* ow2 = (const float*)d_in[8];
    const float* ob2 = (const float*)d_in[9];
    const float* mw1 = (const float*)d_in[10];
    const float* mb1 = (const float*)d_in[11];
    const float* mw2 = (const float*)d_in[12];
    const float* mb2 = (const float*)d_in[13];
    const float* sw1 = (const float*)d_in[14];
    const float* sb1 = (const float*)d_in[15];
    const float* sw2 = (const float*)d_in[16];
    const float* sb2 = (const float*)d_in[17];
    float* out = (float*)d_out;

    const int rows = in_sizes[1] / 8;  // B*T = 819200
    const int grid = 1024;             // R16 config (best: 146us)
    hipLaunchKernelGGL(latent_ode_t, dim3(grid), dim3(256), 0, stream,
                       dt, x, jw1, jb1, jw2, jb2, ow1, ob1, ow2, ob2,
                       mw1, mb1, mw2, mb2, sw1, sb1, sw2, sb2, out, rows);
}